// Round 15
// baseline (284.307 us; speedup 1.0000x reference)
//
#include <hip/hip_runtime.h>
#include <hip/hip_bf16.h>
#include <hip/hip_fp8.h>
#include <math.h>

#define NB 4096     // batch (= B); label of row n is labels[n % NB]
#define NN 8192     // N = B * n_views
#define DD 128      // feature dim (bytes per fp8 row)
#define NCLS 100    // label values 0..99
#define NSPLIT 16   // j-splits; 512 cols per block
#define CHUNK 64    // cols per LDS-staged chunk (R12-proven; 128 spilled, R14)
#define NCHUNK 8    // 512 / 64

constexpr float INV_T = 14.285714285714286f;   // 1/0.07 (= subtracted row max M)
constexpr float EC1   = 20.609929155556620f;   // INV_T * log2(e); inputs scaled by sqrt(EC1)
constexpr float SQE   = 4.5398160926378074f;   // sqrt(EC1)
constexpr float EC0   = -20.609929155556620f;  // exp arg shift, applied in k_final as 2^EC0
constexpr float LN2   = 0.6931471805599453f;

typedef unsigned char u8;
typedef __attribute__((ext_vector_type(8))) int   v8i;
typedef __attribute__((ext_vector_type(4))) int   v4i;
typedef __attribute__((ext_vector_type(4))) float f32x4;

__device__ __forceinline__ float fp8tof(u8 b) {
    __hip_fp8_e4m3 t; t.__x = b; return (float)t;
}

// ---- kernel 1: normalize, scale by sqrt(EC1), quantize fp8 e4m3; selfdot_s ----
__global__ __launch_bounds__(256) void k_norm(const float* __restrict__ feat,
                                              u8* __restrict__ fb8,
                                              float* __restrict__ selfdot,
                                              float* __restrict__ out) {
    const int gid = blockIdx.x * 256 + threadIdx.x;
    if (gid == 0) out[0] = 0.0f;               // k_final atomicAdds into out
    const int r    = gid >> 6;                 // one wave per row
    const int lane = threadIdx.x & 63;
    const float2 v = ((const float2*)(feat + (size_t)r * DD))[lane];
    float ss = v.x * v.x + v.y * v.y;
#pragma unroll
    for (int off = 1; off < 64; off <<= 1) ss += __shfl_xor(ss, off, 64);
    const float scale = SQE / fmaxf(sqrtf(ss), 1e-12f);   // q = f_hat * sqrt(EC1)
    const __hip_fp8_e4m3 qx(v.x * scale), qy(v.y * scale);
    const unsigned short pack = (unsigned short)qx.__x |
                                ((unsigned short)qy.__x << 8);
    ((unsigned short*)(fb8 + (size_t)r * DD))[lane] = pack;
    // selfdot of the SCALED quantized row (= EC1 * raw selfdot; matches MFMA diagonal)
    const float xb = (float)qx, yb = (float)qy;
    float s2 = xb * xb + yb * yb;
#pragma unroll
    for (int off = 1; off < 64; off <<= 1) s2 += __shfl_xor(s2, off, 64);
    if (lane == 0) selfdot[r] = s2;
}

// stage one 64-col chunk's fp8 B-fragments into LDS, fragment-major (R12-verified).
// Pair p = jt*2 + half (8 pairs of 1 KB); wave w stages pairs 2w, 2w+1.
// LDS dst = wave-uniform base + lane*16 (HW rule); per-lane GLOBAL address
// does the fragment gather.
__device__ __forceinline__ void stage_chunk(const u8* __restrict__ fb8, u8* sbuf,
                                            int jb, int w, int n15, int q) {
#pragma unroll
    for (int h = 0; h < 2; ++h) {
        const int p = w * 2 + h;
        const u8* g = fb8 + (size_t)(jb + (p >> 1) * 16 + n15) * DD + q * 32 + (p & 1) * 16;
        __builtin_amdgcn_global_load_lds(
            (const __attribute__((address_space(1))) void*)g,
            (__attribute__((address_space(3))) void*)(sbuf + p * 1024),
            16, 0, 0);
    }
}

// ---- kernel 2: F*F^T sumexp via MX-fp8 K=128 MFMA; NO masks/labels ----
// Epilogue per element: exp2 + accumulate (scale folded into inputs, R14-verified).
// Block: 128 rows x 512 cols; 4 waves of 32 rows; CHUNK=64 (R12-proven geometry).
// Grid 1024 = 64 rb x 16 js, 4 blocks/CU. The last NCLS blocks additionally
// compute class sums S_c + counts after their main loop (no extra dispatch).
__global__ __launch_bounds__(256, 4) void k_main(const u8* __restrict__ fb8,
                                                 const int* __restrict__ labels,
                                                 float* __restrict__ g_se,
                                                 float* __restrict__ S,
                                                 int* __restrict__ counts) {
    __shared__ u8 sB[2][CHUNK * DD];   // 2 x 8 KB, fragment-major

    const int tid  = threadIdx.x;
    const int lane = tid & 63;
    const int w    = tid >> 6;                  // 0..3
    const int rb   = blockIdx.x >> 4;           // 0..63
    const int js   = blockIdx.x & (NSPLIT - 1); // 0..15
    const int i0   = rb * 128 + w * 32;
    const int jb0  = js * 512;
    const int q    = lane >> 4;
    const int n15  = lane & 15;

    // A fragments: 2 row-tiles, full K=128 (8 VGPRs each). Layout HW-verified (R12/R14).
    v8i af[2];
#pragma unroll
    for (int tt = 0; tt < 2; ++tt) {
        const u8* rp = fb8 + (size_t)(i0 + tt * 16 + n15) * DD + q * 32;
        const v4i lo = *(const v4i*)rp;
        const v4i hi = *(const v4i*)(rp + 16);
        v8i a;
#pragma unroll
        for (int k = 0; k < 4; ++k) { a[k] = lo[k]; a[4 + k] = hi[k]; }
        af[tt] = a;
    }

    float a_se[8] = {};

    stage_chunk(fb8, &sB[0][0], jb0, w, n15, q);
    __syncthreads();

    for (int c = 0; c < NCHUNK; ++c) {
        if (c + 1 < NCHUNK)
            stage_chunk(fb8, &sB[(c + 1) & 1][0], jb0 + (c + 1) * CHUNK, w, n15, q);
        const u8* sb = &sB[c & 1][0];
#pragma unroll
        for (int jt = 0; jt < 4; ++jt) {
            const v4i lo = *(const v4i*)(sb + (jt * 2 + 0) * 1024 + lane * 16);
            const v4i hi = *(const v4i*)(sb + (jt * 2 + 1) * 1024 + lane * 16);
            v8i bb;
#pragma unroll
            for (int k = 0; k < 4; ++k) { bb[k] = lo[k]; bb[4 + k] = hi[k]; }
            f32x4 a0 = {0.f, 0.f, 0.f, 0.f}, a1 = {0.f, 0.f, 0.f, 0.f};
            // cbsz=0 (A=fp8 e4m3), blgp=0 (B=fp8); scale bytes 0x7F = e8m0 1.0
            a0 = __builtin_amdgcn_mfma_scale_f32_16x16x128_f8f6f4(
                     af[0], bb, a0, 0, 0, 0, 0x7F7F7F7F, 0, 0x7F7F7F7F);
            a1 = __builtin_amdgcn_mfma_scale_f32_16x16x128_f8f6f4(
                     af[1], bb, a1, 0, 0, 0, 0x7F7F7F7F, 0, 0x7F7F7F7F);
#pragma unroll
            for (int r = 0; r < 4; ++r) {
                a_se[r]     += __builtin_amdgcn_exp2f(a0[r]);   // arg pre-scaled by EC1
                a_se[4 + r] += __builtin_amdgcn_exp2f(a1[r]);
            }
        }
        __syncthreads();
    }

    // 16 lanes per quad share the same rows; reduce, single plain store each
#pragma unroll
    for (int s = 0; s < 8; ++s) {
        float v = a_se[s];
#pragma unroll
        for (int off = 1; off < 16; off <<= 1) v += __shfl_xor(v, off, 64);
        if (n15 == 0)
            g_se[js * NN + i0 + (s >> 2) * 16 + q * 4 + (s & 3)] = v;
    }

    // ---- last NCLS blocks: class sum S_c + count (block owns class c) ----
    if (blockIdx.x >= 1024 - NCLS) {
        const int c = blockIdx.x - (1024 - NCLS);
        __syncthreads();                        // sB reuse safe
        int* list = (int*)&sB[0][0];            // 16 KB total = NB*4
        __shared__ int lcnt;
        if (tid == 0) lcnt = 0;
        __syncthreads();
        for (int b = tid; b < NB; b += 256)
            if (labels[b] == c) list[atomicAdd(&lcnt, 1)] = b;
        __syncthreads();
        const int cnt = lcnt;
        const int d = tid & 127;
        const int h = tid >> 7;                 // which view-row of the pair
        float acc0 = 0.0f, acc1 = 0.0f;
        int i = 0;
        for (; i + 1 < cnt; i += 2) {           // 2-way unroll: loads in flight
            const int b0 = list[i], b1 = list[i + 1];
            acc0 += fp8tof(fb8[(size_t)(b0 + h * NB) * DD + d]);
            acc1 += fp8tof(fb8[(size_t)(b1 + h * NB) * DD + d]);
        }
        if (i < cnt) acc0 += fp8tof(fb8[(size_t)(list[i] + h * NB) * DD + d]);
        __syncthreads();
        float* Sl = (float*)&sB[0][0];
        Sl[tid] = acc0 + acc1;
        __syncthreads();
        if (tid < 128) S[c * DD + tid] = Sl[tid] + Sl[tid + 128];
        if (tid == 0) counts[c] = cnt;
    }
}

// ---- kernel 3: per-row loss via algebraic possum (R14-verified) -> atomic mean ----
__global__ __launch_bounds__(256) void k_final(const u8* __restrict__ fb8,
                                               const int* __restrict__ labels,
                                               const float* __restrict__ g_se,
                                               const float* __restrict__ S,
                                               const int* __restrict__ counts,
                                               const float* __restrict__ selfdot,
                                               float* __restrict__ out) {
    const int r = blockIdx.x * 256 + threadIdx.x;
    const int c = labels[r & (NB - 1)];
    float se = 0.0f;
#pragma unroll
    for (int t = 0; t < NSPLIT; ++t) se += g_se[t * NN + r];

    // s1_s = dot(q_i, S_c) in fp32 (scaled domain)
    const u8* fp = fb8 + (size_t)r * DD;
    const float* sp = S + c * DD;
    float s1 = 0.0f;
#pragma unroll
    for (int k = 0; k < DD; k += 4) {
        const unsigned int u = *(const unsigned int*)(fp + k);
        const float4 sv = *(const float4*)(sp + k);
        s1 = fmaf(fp8tof(u & 0xff), sv.x,
             fmaf(fp8tof((u >> 8) & 0xff), sv.y,
             fmaf(fp8tof((u >> 16) & 0xff), sv.z,
             fmaf(fp8tof(u >> 24), sv.w, s1))));
    }
    const float sd = selfdot[r];                       // scaled selfdot (= EC1 * raw)
    const float C0 = __builtin_amdgcn_exp2f(EC0);      // 2^-EC1
    se = (se - __builtin_amdgcn_exp2f(sd)) * C0;       // true sum_{j!=i} exp(l-M)
    const float ct = (float)(2 * counts[c] - 1);       // positives excl. diagonal
    const float possum = INV_T * ((s1 - sd) * (1.0f / EC1) - ct);
    const float lg  = __builtin_amdgcn_logf(se + 1e-12f) * LN2;
    const float mlpp = (possum - ct * lg) / fmaxf(ct, 1.0f);
    float v = -mlpp * (1.0f / (float)NN);
#pragma unroll
    for (int off = 1; off < 64; off <<= 1) v += __shfl_xor(v, off, 64);
    __shared__ float sred[4];
    if ((threadIdx.x & 63) == 0) sred[threadIdx.x >> 6] = v;
    __syncthreads();
    if (threadIdx.x == 0) atomicAdd(out, sred[0] + sred[1] + sred[2] + sred[3]);
}

extern "C" void kernel_launch(void* const* d_in, const int* in_sizes, int n_in,
                              void* d_out, int out_size, void* d_ws, size_t ws_size,
                              hipStream_t stream) {
    const float* feat = (const float*)d_in[0];
    const int* labels = (const int*)d_in[1];
    float* out        = (float*)d_out;
    char* ws          = (char*)d_ws;

    u8* fb8         = (u8*)ws;                                       // 1 MB fp8 (scaled)
    float* g_se     = (float*)(ws + (size_t)1 * 1024 * 1024);        // [16][NN] 512 KB
    float* selfdot  = g_se + NSPLIT * NN;                            // NN f32
    float* S        = selfdot + NN;                                  // NCLS*DD f32 (owner-stored)
    int*   counts   = (int*)(S + NCLS * DD);                         // NCLS i32  (owner-stored)

    k_norm<<<NN / 4, 256, 0, stream>>>(feat, fb8, selfdot, out);
    k_main<<<(NN / 128) * NSPLIT, 256, 0, stream>>>(fb8, labels, g_se, S, counts);
    k_final<<<NN / 256, 256, 0, stream>>>(fb8, labels, g_se, S, counts, selfdot, out);
}

// Round 16
// 89.227 us; speedup vs baseline: 3.1863x; 3.1863x over previous
//
#include <hip/hip_runtime.h>
#include <hip/hip_bf16.h>
#include <hip/hip_fp8.h>
#include <math.h>

#define NB 4096     // batch (= B); label of row n is labels[n % NB]
#define NN 8192     // N = B * n_views
#define DD 128      // feature dim (bytes per fp8 row)
#define NCLS 100    // label values 0..99
#define NSPLIT 16   // j-splits; 512 cols per block
#define CHUNK 64    // cols per LDS-staged chunk (R12-proven geometry)
#define NCHUNK 8    // 512 / 64

constexpr float INV_T = 14.285714285714286f;   // 1/0.07 (= subtracted row max M)
constexpr float EC1   = 20.609929155556620f;   // INV_T * log2(e); inputs scaled by sqrt(EC1)
constexpr float SQE   = 4.5398160926378074f;   // sqrt(EC1)
constexpr float EC0   = -20.609929155556620f;  // exp arg shift, applied in k_final as 2^EC0
constexpr float LN2   = 0.6931471805599453f;

typedef unsigned char u8;
typedef __attribute__((ext_vector_type(8))) int   v8i;
typedef __attribute__((ext_vector_type(4))) int   v4i;
typedef __attribute__((ext_vector_type(4))) float f32x4;

__device__ __forceinline__ float fp8tof(u8 b) {
    __hip_fp8_e4m3 t; t.__x = b; return (float)t;
}

// ---- kernel 1: normalize, scale by sqrt(EC1), quantize fp8 e4m3; selfdot_s ----
__global__ __launch_bounds__(256) void k_norm(const float* __restrict__ feat,
                                              u8* __restrict__ fb8,
                                              float* __restrict__ selfdot,
                                              float* __restrict__ out) {
    const int gid = blockIdx.x * 256 + threadIdx.x;
    if (gid == 0) out[0] = 0.0f;               // k_final atomicAdds into out
    const int r    = gid >> 6;                 // one wave per row
    const int lane = threadIdx.x & 63;
    const float2 v = ((const float2*)(feat + (size_t)r * DD))[lane];
    float ss = v.x * v.x + v.y * v.y;
#pragma unroll
    for (int off = 1; off < 64; off <<= 1) ss += __shfl_xor(ss, off, 64);
    const float scale = SQE / fmaxf(sqrtf(ss), 1e-12f);   // q = f_hat * sqrt(EC1)
    const __hip_fp8_e4m3 qx(v.x * scale), qy(v.y * scale);
    const unsigned short pack = (unsigned short)qx.__x |
                                ((unsigned short)qy.__x << 8);
    ((unsigned short*)(fb8 + (size_t)r * DD))[lane] = pack;
    // selfdot of the SCALED quantized row (= EC1 * raw selfdot; matches MFMA diagonal)
    const float xb = (float)qx, yb = (float)qy;
    float s2 = xb * xb + yb * yb;
#pragma unroll
    for (int off = 1; off < 64; off <<= 1) s2 += __shfl_xor(s2, off, 64);
    if (lane == 0) selfdot[r] = s2;
}

// ---- kernel 2: class sums S_c, one block per class (R11-proven structure) ----
// Block owns its class -> plain stores, no global atomics, no zero-init.
__global__ __launch_bounds__(256) void k_csum(const u8* __restrict__ fb8,
                                              const int* __restrict__ labels,
                                              float* __restrict__ S,
                                              int* __restrict__ counts) {
    __shared__ int list[NB];       // 16 KB match list
    __shared__ float Sl[256];
    __shared__ int lcnt;
    const int tid = threadIdx.x;
    const int c   = blockIdx.x;
    if (tid == 0) lcnt = 0;
    __syncthreads();
    for (int b = tid; b < NB; b += 256)
        if (labels[b] == c) list[atomicAdd(&lcnt, 1)] = b;
    __syncthreads();
    const int cnt = lcnt;
    const int d = tid & 127;
    const int h = tid >> 7;        // which view-row of the pair
    float acc0 = 0.0f, acc1 = 0.0f;
    int i = 0;
    for (; i + 1 < cnt; i += 2) {  // 2-way unroll: independent loads in flight
        const int b0 = list[i], b1 = list[i + 1];
        acc0 += fp8tof(fb8[(size_t)(b0 + h * NB) * DD + d]);
        acc1 += fp8tof(fb8[(size_t)(b1 + h * NB) * DD + d]);
    }
    if (i < cnt) acc0 += fp8tof(fb8[(size_t)(list[i] + h * NB) * DD + d]);
    Sl[tid] = acc0 + acc1;
    __syncthreads();
    if (tid < 128) S[c * DD + tid] = Sl[tid] + Sl[tid + 128];
    if (tid == 0) counts[c] = cnt;
}

// stage one 64-col chunk's fp8 B-fragments into LDS, fragment-major (R12-verified).
// Pair p = jt*2 + half (8 pairs of 1 KB); wave w stages pairs 2w, 2w+1.
// LDS dst = wave-uniform base + lane*16 (HW rule); per-lane GLOBAL address
// does the fragment gather.
__device__ __forceinline__ void stage_chunk(const u8* __restrict__ fb8, u8* sbuf,
                                            int jb, int w, int n15, int q) {
#pragma unroll
    for (int h = 0; h < 2; ++h) {
        const int p = w * 2 + h;
        const u8* g = fb8 + (size_t)(jb + (p >> 1) * 16 + n15) * DD + q * 32 + (p & 1) * 16;
        __builtin_amdgcn_global_load_lds(
            (const __attribute__((address_space(1))) void*)g,
            (__attribute__((address_space(3))) void*)(sbuf + p * 1024),
            16, 0, 0);
    }
}

// ---- kernel 3: F*F^T sumexp via MX-fp8 K=128 MFMA; exp2-only epilogue ----
// EXACT R12 block/loop geometry (never spilled): 128 rows x 512 cols, 4 waves
// of 32 rows, CHUNK=64 double-buffer, (256,4). Single-purpose kernel: no
// labels, no masks, no tail (R14/R15 lesson: fusing the class-sum tail into
// this kernel wrecks register allocation -> 400 MB scratch spill).
__global__ __launch_bounds__(256, 4) void k_main(const u8* __restrict__ fb8,
                                                 float* __restrict__ g_se) {
    __shared__ u8 sB[2][CHUNK * DD];   // 2 x 8 KB, fragment-major

    const int tid  = threadIdx.x;
    const int lane = tid & 63;
    const int w    = tid >> 6;                  // 0..3
    const int rb   = blockIdx.x >> 4;           // 0..63
    const int js   = blockIdx.x & (NSPLIT - 1); // 0..15
    const int i0   = rb * 128 + w * 32;
    const int jb0  = js * 512;
    const int q    = lane >> 4;
    const int n15  = lane & 15;

    // A fragments: 2 row-tiles, full K=128 (8 VGPRs each). Layout HW-verified (R12/R14).
    v8i af[2];
#pragma unroll
    for (int tt = 0; tt < 2; ++tt) {
        const u8* rp = fb8 + (size_t)(i0 + tt * 16 + n15) * DD + q * 32;
        const v4i lo = *(const v4i*)rp;
        const v4i hi = *(const v4i*)(rp + 16);
        v8i a;
#pragma unroll
        for (int k = 0; k < 4; ++k) { a[k] = lo[k]; a[4 + k] = hi[k]; }
        af[tt] = a;
    }

    float a_se[8] = {};

    stage_chunk(fb8, &sB[0][0], jb0, w, n15, q);
    __syncthreads();

#pragma unroll 1   // forbid multi-chunk software pipelining (R14 spill mode)
    for (int c = 0; c < NCHUNK; ++c) {
        if (c + 1 < NCHUNK)
            stage_chunk(fb8, &sB[(c + 1) & 1][0], jb0 + (c + 1) * CHUNK, w, n15, q);
        const u8* sb = &sB[c & 1][0];
#pragma unroll
        for (int jt = 0; jt < 4; ++jt) {
            const v4i lo = *(const v4i*)(sb + (jt * 2 + 0) * 1024 + lane * 16);
            const v4i hi = *(const v4i*)(sb + (jt * 2 + 1) * 1024 + lane * 16);
            v8i bb;
#pragma unroll
            for (int k = 0; k < 4; ++k) { bb[k] = lo[k]; bb[4 + k] = hi[k]; }
            f32x4 a0 = {0.f, 0.f, 0.f, 0.f}, a1 = {0.f, 0.f, 0.f, 0.f};
            // cbsz=0 (A=fp8 e4m3), blgp=0 (B=fp8); scale bytes 0x7F = e8m0 1.0
            a0 = __builtin_amdgcn_mfma_scale_f32_16x16x128_f8f6f4(
                     af[0], bb, a0, 0, 0, 0, 0x7F7F7F7F, 0, 0x7F7F7F7F);
            a1 = __builtin_amdgcn_mfma_scale_f32_16x16x128_f8f6f4(
                     af[1], bb, a1, 0, 0, 0, 0x7F7F7F7F, 0, 0x7F7F7F7F);
#pragma unroll
            for (int r = 0; r < 4; ++r) {
                a_se[r]     += __builtin_amdgcn_exp2f(a0[r]);   // arg pre-scaled by EC1
                a_se[4 + r] += __builtin_amdgcn_exp2f(a1[r]);
            }
        }
        __syncthreads();
    }

    // 16 lanes per quad share the same rows; reduce, single plain store each
#pragma unroll
    for (int s = 0; s < 8; ++s) {
        float v = a_se[s];
#pragma unroll
        for (int off = 1; off < 16; off <<= 1) v += __shfl_xor(v, off, 64);
        if (n15 == 0)
            g_se[js * NN + i0 + (s >> 2) * 16 + q * 4 + (s & 3)] = v;
    }
}

// ---- kernel 4: per-row loss via algebraic possum (R14/R15-verified) ----
__global__ __launch_bounds__(256) void k_final(const u8* __restrict__ fb8,
                                               const int* __restrict__ labels,
                                               const float* __restrict__ g_se,
                                               const float* __restrict__ S,
                                               const int* __restrict__ counts,
                                               const float* __restrict__ selfdot,
                                               float* __restrict__ out) {
    const int r = blockIdx.x * 256 + threadIdx.x;
    const int c = labels[r & (NB - 1)];
    float se = 0.0f;
#pragma unroll
    for (int t = 0; t < NSPLIT; ++t) se += g_se[t * NN + r];

    // s1_s = dot(q_i, S_c) in fp32 (scaled domain)
    const u8* fp = fb8 + (size_t)r * DD;
    const float* sp = S + c * DD;
    float s1 = 0.0f;
#pragma unroll
    for (int k = 0; k < DD; k += 4) {
        const unsigned int u = *(const unsigned int*)(fp + k);
        const float4 sv = *(const float4*)(sp + k);
        s1 = fmaf(fp8tof(u & 0xff), sv.x,
             fmaf(fp8tof((u >> 8) & 0xff), sv.y,
             fmaf(fp8tof((u >> 16) & 0xff), sv.z,
             fmaf(fp8tof(u >> 24), sv.w, s1))));
    }
    const float sd = selfdot[r];                       // scaled selfdot (= EC1 * raw)
    const float C0 = __builtin_amdgcn_exp2f(EC0);      // 2^-EC1
    se = (se - __builtin_amdgcn_exp2f(sd)) * C0;       // true sum_{j!=i} exp(l-M)
    const float ct = (float)(2 * counts[c] - 1);       // positives excl. diagonal
    const float possum = INV_T * ((s1 - sd) * (1.0f / EC1) - ct);
    const float lg  = __builtin_amdgcn_logf(se + 1e-12f) * LN2;
    const float mlpp = (possum - ct * lg) / fmaxf(ct, 1.0f);
    float v = -mlpp * (1.0f / (float)NN);
#pragma unroll
    for (int off = 1; off < 64; off <<= 1) v += __shfl_xor(v, off, 64);
    __shared__ float sred[4];
    if ((threadIdx.x & 63) == 0) sred[threadIdx.x >> 6] = v;
    __syncthreads();
    if (threadIdx.x == 0) atomicAdd(out, sred[0] + sred[1] + sred[2] + sred[3]);
}

extern "C" void kernel_launch(void* const* d_in, const int* in_sizes, int n_in,
                              void* d_out, int out_size, void* d_ws, size_t ws_size,
                              hipStream_t stream) {
    const float* feat = (const float*)d_in[0];
    const int* labels = (const int*)d_in[1];
    float* out        = (float*)d_out;
    char* ws          = (char*)d_ws;

    u8* fb8         = (u8*)ws;                                       // 1 MB fp8 (scaled)
    float* g_se     = (float*)(ws + (size_t)1 * 1024 * 1024);        // [16][NN] 512 KB
    float* selfdot  = g_se + NSPLIT * NN;                            // NN f32
    float* S        = selfdot + NN;                                  // NCLS*DD f32 (owner-stored)
    int*   counts   = (int*)(S + NCLS * DD);                         // NCLS i32  (owner-stored)

    k_norm<<<NN / 4, 256, 0, stream>>>(feat, fb8, selfdot, out);
    k_csum<<<NCLS, 256, 0, stream>>>(fb8, labels, S, counts);
    k_main<<<(NN / 128) * NSPLIT, 256, 0, stream>>>(fb8, g_se);
    k_final<<<NN / 256, 256, 0, stream>>>(fb8, labels, g_se, S, counts, selfdot, out);
}